// Round 1
// baseline (725.844 us; speedup 1.0000x reference)
//
#include <hip/hip_runtime.h>
#include <stdint.h>

#define EPSF 1e-5f

typedef __bf16 bf16;
typedef __attribute__((ext_vector_type(8))) __bf16 bf16x8;
typedef __attribute__((ext_vector_type(4))) float f32x4;

// ---------------- quantization + BN-fold + MFMA-fragment prepack -----------------
// k-order for all GEMMs: k = (kh*3+kw)*CIN + c   (c-minor => 8 consecutive k = 8
// consecutive input channels at fixed tap => contiguous LDS reads on the B side).
// A-fragment prepack layout: wpk[ks][mt][lane][j] ; lane = kq*16 + (o&15), j = k&7.
struct QArgs {
  const float* w[5];
  const float* g[5];
  const float* bb[5];
  const float* m[5];
  const float* v[5];
  bf16* wpk[3];
  float* alpha[3];
  float* beta[3];
};

__global__ __launch_bounds__(256)
void quant_kernel(QArgs qa) {
  __shared__ float sbuf[4096];
  const int tid = threadIdx.x;
  const int blk = blockIdx.x;
  int layer, o;
  if (blk < 128)      { layer = 0; o = blk; }
  else if (blk < 192) { layer = 1; o = blk - 128; }
  else if (blk < 256) { layer = 2; o = blk - 192; }
  else if (blk < 320) { layer = 3; o = blk - 256; }
  else                { layer = 4; o = blk - 320; }
  const int I_[5]     = {256, 256, 64, 64, 64};
  const int gemm_[5]  = {0, 0, 1, 1, 2};
  const int obase_[5] = {0, 128, 0, 64, 0};
  const int gNMT[3]   = {12, 8, 4};
  const int I = I_[layer];
  const int n = I * 9;                      // 2304 or 576
  const int npad = (n > 1024) ? 4096 : 1024;
  const float* w = qa.w[layer] + (size_t)o * n;

  // load |w| (pad with +inf), bitonic sort ascending
  for (int i = tid; i < npad; i += 256)
    sbuf[i] = (i < n) ? fabsf(w[i]) : 3.4e38f;
  __syncthreads();
  for (int k = 2; k <= npad; k <<= 1) {
    for (int j = k >> 1; j > 0; j >>= 1) {
      for (int i = tid; i < npad; i += 256) {
        int ixj = i ^ j;
        if (ixj > i) {
          float a = sbuf[i], c = sbuf[ixj];
          if ((a > c) == ((i & k) == 0)) { sbuf[i] = c; sbuf[ixj] = a; }
        }
      }
      __syncthreads();
    }
  }
  // even count -> average of the two middle elements (matches np.median)
  const float s = fmaxf(0.5f * (sbuf[n / 2 - 1] + sbuf[n / 2]), EPSF);
  const int g  = gemm_[layer];
  const int ob = obase_[layer];
  const int NMT = gNMT[g];
  if (tid == 0) {
    float inv = qa.g[layer][o] / sqrtf(qa.v[layer][o] + EPSF);
    qa.alpha[g][ob + o] = s * inv;                              // folds ternary scale
    qa.beta[g][ob + o]  = qa.bb[layer][o] - qa.m[layer][o] * inv;
  }
  const int og  = ob + o;
  const int mt  = og >> 4;
  const int l16 = og & 15;
  bf16* wp = qa.wpk[g];
  for (int i = tid; i < n; i += 256) {
    float t = rintf(w[i] / s);                 // rintf = round-half-even, same as jnp.round
    t = fmaxf(-1.f, fminf(1.f, t));
    int c = i / 9, pos = i % 9;                // w layout [I][3][3]
    int k = pos * I + c;
    int ks = k >> 5, kq = (k >> 3) & 3, jj = k & 7;
    wp[((size_t)((ks * NMT + mt) * 64 + kq * 16 + l16)) * 8 + jj] = (bf16)t;
  }
}

// ---------------- implicit-GEMM conv3x3 (pad=1) with fused BN+SiLU -----------------
// Block: 512 thr = 8 waves. M-tile = 128 pixels (2 rows x 64 w); wave -> 16 pixels.
// Each wave computes all COUT = NMT*16 channels. MFMA 16x16x32 bf16:
//   Src0 = A = ternary weights  [m=channel][k],  Src1 = B = activations [k][n=pixel].
// LDS x-tile: [row(4)][col(68 pitch)][c(32, pitch 40)] bf16; col pitch = 80B (16B
// aligned, bank-spread). b_frag = 8 consecutive c at (row+kh, col+kw) -> ds_read_b128.
template<int CIN, int NMT, int C1, bool IN_F32>
__global__ __launch_bounds__(512)
void conv_k(const void* __restrict__ inp,
            const bf16* __restrict__ wpk,
            const float* __restrict__ alpha,
            const float* __restrict__ beta,
            float* __restrict__ out, int chan_off,
            bf16* __restrict__ padout) {
  __shared__ bf16 xs[4 * 68 * 40];      // 21.76 KB
  __shared__ bf16 wlds[NMT * 64 * 8];   // NMT KB

  const int tid  = threadIdx.x;
  const int wave = tid >> 6;
  const int lane = tid & 63;
  const int q    = lane >> 4;
  const int t16  = lane & 15;
  const int r_w  = wave >> 2;           // row within block (0..1)
  const int wseg = (wave & 3) << 4;     // w-segment base (0,16,32,48)

  const int mblk = blockIdx.x;
  const int b  = mblk >> 5;             // batch
  const int h0 = (mblk & 31) << 1;      // first output row

  f32x4 acc[NMT] = {};

  for (int c0 = 0; c0 < CIN; c0 += 32) {
    __syncthreads();                    // protect xs from previous iter's readers
    if (IN_F32) {
      const float* x = (const float*)inp;
      for (int idx = tid; idx < 4 * 66 * 32; idx += 512) {
        int j = idx % 66;               // padded col 0..65 (ww = j-1)
        int rc = idx / 66;
        int r = rc & 3, c = rc >> 2;
        int hh = h0 - 1 + r, ww = j - 1;
        float val = 0.f;
        if ((unsigned)hh < 64u && (unsigned)ww < 64u)
          val = x[((size_t)(b * CIN + c0 + c) * 64 + hh) * 64 + ww];
        xs[(r * 68 + j) * 40 + c] = (bf16)val;
      }
    } else {
      const bf16* xp = (const bf16*)inp;   // zero-padded [B][CIN][66][72]
      for (int idx = tid; idx < 4 * 66 * 32; idx += 512) {
        int j = idx % 66;
        int rc = idx / 66;
        int r = rc & 3, c = rc >> 2;
        xs[(r * 68 + j) * 40 + c] =
            xp[((size_t)(b * CIN + c0 + c) * 66 + (h0 + r)) * 72 + j];
      }
    }
#pragma unroll
    for (int pos = 0; pos < 9; ++pos) {
      const int ks = (pos * CIN + c0) >> 5;
      // stage this K-step's A fragments (NMT KB) into LDS
      for (int i = tid; i < NMT * 64; i += 512) {
        const uint4 vv = *(const uint4*)(wpk + ((size_t)ks * NMT * 64 + i) * 8);
        *(uint4*)&wlds[i * 8] = vv;
      }
      __syncthreads();
      const int kh = pos / 3, kw = pos % 3;
      const int row = r_w + kh, col = wseg + t16 + kw;
      const bf16x8 bfrag = *(const bf16x8*)&xs[(row * 68 + col) * 40 + q * 8];
#pragma unroll
      for (int mt = 0; mt < NMT; ++mt) {
        const bf16x8 afrag = *(const bf16x8*)&wlds[(mt * 64 + lane) * 8];
        acc[mt] = __builtin_amdgcn_mfma_f32_16x16x32_bf16(afrag, bfrag, acc[mt], 0, 0, 0);
      }
      __syncthreads();                  // before wlds is overwritten
    }
  }

  // epilogue: BN fold + SiLU; D[m=4q+i][n=t16] per mt
  const int h = h0 + r_w, wv = wseg + t16;
#pragma unroll
  for (int mt = 0; mt < NMT; ++mt) {
    const int obt = mt * 16 + 4 * q;
#pragma unroll
    for (int i = 0; i < 4; ++i) {
      const int o = obt + i;
      float v = acc[mt][i] * alpha[o] + beta[o];
      float sg = v / (1.f + __expf(-v));
      if (o < C1) {
        out[((size_t)(b * 256 + chan_off + o) * 64 + h) * 64 + wv] = sg;
      } else {
        padout[((size_t)(b * 64 + (o - C1)) * 66 + (h + 1)) * 72 + (wv + 1)] = (bf16)sg;
      }
    }
  }
}

extern "C" void kernel_launch(void* const* d_in, const int* in_sizes, int n_in,
                              void* d_out, int out_size, void* d_ws, size_t ws_size,
                              hipStream_t stream) {
  QArgs qa;
  const float* x = (const float*)d_in[0];
  for (int L = 0; L < 5; ++L) {
    qa.w[L]  = (const float*)d_in[1 + 5 * L];
    qa.g[L]  = (const float*)d_in[2 + 5 * L];
    qa.bb[L] = (const float*)d_in[3 + 5 * L];
    qa.m[L]  = (const float*)d_in[4 + 5 * L];
    qa.v[L]  = (const float*)d_in[5 + 5 * L];
  }
  // workspace carve (all 16B-aligned): ~40.1 MB total
  char* p = (char*)d_ws;
  bf16* wpk1 = (bf16*)p; p += (size_t)192 * 2304 * 2;   // 884,736 B
  bf16* wpk2 = (bf16*)p; p += (size_t)128 * 576 * 2;    // 147,456 B
  bf16* wpk3 = (bf16*)p; p += (size_t)64 * 576 * 2;     //  73,728 B
  float* a1 = (float*)p; p += 1024;
  float* b1 = (float*)p; p += 1024;
  float* a2 = (float*)p; p += 1024;
  float* b2 = (float*)p; p += 1024;
  float* a3 = (float*)p; p += 1024;
  float* b3 = (float*)p; p += 1024;
  const size_t padsz = (size_t)32 * 64 * 66 * 72;       // elements per padded buffer
  bf16* stem = (bf16*)p; p += padsz * 2;                // 19.46 MB
  bf16* tbuf = (bf16*)p; p += padsz * 2;                // 19.46 MB
  qa.wpk[0] = wpk1; qa.wpk[1] = wpk2; qa.wpk[2] = wpk3;
  qa.alpha[0] = a1; qa.alpha[1] = a2; qa.alpha[2] = a3;
  qa.beta[0]  = b1; qa.beta[1]  = b2; qa.beta[2]  = b3;

  // zero padded intermediate buffers (borders must be 0; ws is poisoned each call)
  hipMemsetAsync(stem, 0, padsz * 2, stream);
  hipMemsetAsync(tbuf, 0, padsz * 2, stream);

  quant_kernel<<<384, 256, 0, stream>>>(qa);

  // stage 1: x -> c3 (out ch 0..127, silu) + stem (silu, bf16 padded)
  conv_k<256, 12, 128, true ><<<1024, 512, 0, stream>>>(x,    wpk1, a1, b1, (float*)d_out, 0,   stem);
  // stage 2: stem -> c5 (out ch 128..191) + t (silu, bf16 padded)
  conv_k< 64,  8,  64, false><<<1024, 512, 0, stream>>>(stem, wpk2, a2, b2, (float*)d_out, 128, tbuf);
  // stage 3: t -> c7 (out ch 192..255)
  conv_k< 64,  4,  64, false><<<1024, 512, 0, stream>>>(tbuf, wpk3, a3, b3, (float*)d_out, 192, nullptr);
}

// Round 2
// 591.365 us; speedup vs baseline: 1.2274x; 1.2274x over previous
//
#include <hip/hip_runtime.h>
#include <stdint.h>

#define EPSF 1e-5f

typedef __bf16 bf16;
typedef __attribute__((ext_vector_type(8))) __bf16 bf16x8;
typedef __attribute__((ext_vector_type(4))) float f32x4;

// ---------------- quantization + BN-fold + MFMA-fragment prepack -----------------
// k-order: k = (kh*3+kw)*CIN + c (c-minor). A-frag prepack: wpk[ks][mt][lane][j],
// lane = kq*16 + (o&15), j = k&7.  (verified in round 1)
struct QArgs {
  const float* w[5];
  const float* g[5];
  const float* bb[5];
  const float* m[5];
  const float* v[5];
  bf16* wpk[3];
  float* alpha[3];
  float* beta[3];
};

__global__ __launch_bounds__(256)
void quant_kernel(QArgs qa) {
  __shared__ float sbuf[4096];
  const int tid = threadIdx.x;
  const int blk = blockIdx.x;
  int layer, o;
  if (blk < 128)      { layer = 0; o = blk; }
  else if (blk < 192) { layer = 1; o = blk - 128; }
  else if (blk < 256) { layer = 2; o = blk - 192; }
  else if (blk < 320) { layer = 3; o = blk - 256; }
  else                { layer = 4; o = blk - 320; }
  const int I_[5]     = {256, 256, 64, 64, 64};
  const int gemm_[5]  = {0, 0, 1, 1, 2};
  const int obase_[5] = {0, 128, 0, 64, 0};
  const int gNMT[3]   = {12, 8, 4};
  const int I = I_[layer];
  const int n = I * 9;
  const int npad = (n > 1024) ? 4096 : 1024;
  const float* w = qa.w[layer] + (size_t)o * n;

  for (int i = tid; i < npad; i += 256)
    sbuf[i] = (i < n) ? fabsf(w[i]) : 3.4e38f;
  __syncthreads();
  for (int k = 2; k <= npad; k <<= 1) {
    for (int j = k >> 1; j > 0; j >>= 1) {
      for (int i = tid; i < npad; i += 256) {
        int ixj = i ^ j;
        if (ixj > i) {
          float a = sbuf[i], c = sbuf[ixj];
          if ((a > c) == ((i & k) == 0)) { sbuf[i] = c; sbuf[ixj] = a; }
        }
      }
      __syncthreads();
    }
  }
  const float s = fmaxf(0.5f * (sbuf[n / 2 - 1] + sbuf[n / 2]), EPSF);
  const int g  = gemm_[layer];
  const int ob = obase_[layer];
  const int NMT = gNMT[g];
  if (tid == 0) {
    float inv = qa.g[layer][o] / sqrtf(qa.v[layer][o] + EPSF);
    qa.alpha[g][ob + o] = s * inv;
    qa.beta[g][ob + o]  = qa.bb[layer][o] - qa.m[layer][o] * inv;
  }
  const int og  = ob + o;
  const int mt  = og >> 4;
  const int l16 = og & 15;
  bf16* wp = qa.wpk[g];
  for (int i = tid; i < n; i += 256) {
    float t = rintf(w[i] / s);
    t = fmaxf(-1.f, fminf(1.f, t));
    int c = i / 9, pos = i % 9;
    int k = pos * I + c;
    int ks = k >> 5, kq = (k >> 3) & 3, jj = k & 7;
    wp[((size_t)((ks * NMT + mt) * 64 + kq * 16 + l16)) * 8 + jj] = (bf16)t;
  }
}

// ---------------- NCHW fp32 -> c-minor bf16 transpose: xT[b][h][w][256] ----------
__global__ __launch_bounds__(256)
void transpose_k(const float* __restrict__ x, bf16* __restrict__ xT) {
  __shared__ float tile[64 * 66];          // [w][c pitch 66] fp32
  const int tid = threadIdx.x;
  const int blk = blockIdx.x;
  const int cg = blk & 3;                  // 64-channel group
  const int h  = (blk >> 2) & 63;
  const int b  = blk >> 8;
  const int w  = tid & 63;
  const int cb = tid >> 6;                 // 0..3
#pragma unroll
  for (int p = 0; p < 16; ++p) {
    int c = cb * 16 + p;                   // 0..63, lanes sweep w -> coalesced
    tile[w * 66 + c] = x[(((size_t)(b * 256 + cg * 64 + c)) * 64 + h) * 64 + w];
  }
  __syncthreads();
#pragma unroll
  for (int p = 0; p < 2; ++p) {
    int id = tid + p * 256;                // 512 chunks = 64 w x 8 chunks-of-8c
    int c8 = id & 7, w2 = id >> 3;
    const float* src = &tile[w2 * 66 + c8 * 8];
    bf16x8 v;
#pragma unroll
    for (int j = 0; j < 8; ++j) v[j] = (bf16)src[j];
    *(bf16x8*)&xT[(((size_t)(b * 64 + h)) * 64 + w2) * 256 + cg * 64 + c8 * 8] = v;
  }
}

// ---------------- implicit-GEMM conv3x3 (pad=1) + fused BN + SiLU ----------------
// Block = 256 thr = 4 waves. Block tile: 128 px (2 rows x 64 w) x NMT*16 channels.
// Wave = all 128 px (8 n-tiles) x MM m-tiles (mt = wave*MM .. +MM-1).
// B staged in LDS (c-minor b128 both sides); A loaded global->VGPR (L2-hot).
// Only 2 barriers per 32-channel c-iter.
template<int CIN, int NMT, int MM, int C1, bool HASPAD>
__global__ __launch_bounds__(256, 2)
void conv_k(const bf16* __restrict__ xin,   // [B][64][64][CIN] c-minor bf16
            const bf16* __restrict__ wpk,
            const float* __restrict__ alpha,
            const float* __restrict__ beta,
            float* __restrict__ out, int chan_off,
            bf16* __restrict__ padout) {    // [B][64][64][64] c-minor bf16
  __shared__ union U { bf16 xs[4 * 66 * 40]; bf16 ep[128 * 72]; } sm;

  const int tid  = threadIdx.x;
  const int wave = tid >> 6;
  const int lane = tid & 63;
  const int q    = lane >> 4;
  const int t16  = lane & 15;
  const int b    = blockIdx.x >> 5;
  const int h0   = (blockIdx.x & 31) << 1;  // 2 output rows per block
  const int mt0  = wave * MM;

  f32x4 acc[8][MM] = {};

  for (int ci = 0; ci < CIN / 32; ++ci) {
    const int c0 = ci * 32;
    __syncthreads();                        // xs safe to overwrite
    // stage 4 rows x 66 cols x 32 ch, all b128
#pragma unroll
    for (int p = 0; p < 5; ++p) {
      int id = tid + p * 256;
      if (id < 1056) {
        int c8 = id & 3;
        int rj = id >> 2;
        int j = rj % 66, r = rj / 66;
        int hh = h0 + r - 1, ww = j - 1;
        bf16x8 v = {};
        if ((unsigned)hh < 64u && (unsigned)ww < 64u)
          v = *(const bf16x8*)&xin[(((size_t)(b * 64 + hh)) * 64 + ww) * CIN + c0 + c8 * 8];
        *(bf16x8*)&sm.xs[(r * 66 + j) * 40 + c8 * 8] = v;
      }
    }
    __syncthreads();
    for (int pos = 0; pos < 9; ++pos) {
      const int kh = pos / 3, kw = pos % 3;
      const int ks = pos * (CIN / 32) + ci;
      bf16x8 af[MM];
#pragma unroll
      for (int mm = 0; mm < MM; ++mm)
        af[mm] = *(const bf16x8*)&wpk[((size_t)((ks * NMT + mt0 + mm) * 64 + lane)) * 8];
#pragma unroll
      for (int nt = 0; nt < 8; ++nt) {
        const int r = (nt >> 2) + kh;
        const int col = (nt & 3) * 16 + t16 + kw;
        const bf16x8 bf = *(const bf16x8*)&sm.xs[(r * 66 + col) * 40 + q * 8];
#pragma unroll
        for (int mm = 0; mm < MM; ++mm)
          acc[nt][mm] = __builtin_amdgcn_mfma_f32_16x16x32_bf16(af[mm], bf, acc[nt][mm], 0, 0, 0);
      }
    }
  }

  // epilogue: in-place BN+SiLU on acc, fp32 NCHW stores for o<C1
#pragma unroll
  for (int nt = 0; nt < 8; ++nt) {
    const int r = nt >> 2, wv = (nt & 3) * 16 + t16;
#pragma unroll
    for (int mm = 0; mm < MM; ++mm) {
      const int ob = (mt0 + mm) * 16 + 4 * q;
#pragma unroll
      for (int i = 0; i < 4; ++i) {
        const int o = ob + i;
        float v = acc[nt][mm][i] * alpha[o] + beta[o];
        float sg = v / (1.f + __expf(-v));
        acc[nt][mm][i] = sg;
        if (o < C1)
          out[(((size_t)(b * 256 + chan_off + o)) * 64 + h0 + r) * 64 + wv] = sg;
      }
    }
  }
  if (HASPAD) {
    __syncthreads();                        // all waves done reading xs
#pragma unroll
    for (int nt = 0; nt < 8; ++nt) {
      const int px = nt * 16 + t16;
#pragma unroll
      for (int mm = 0; mm < MM; ++mm) {
        const int ob = (mt0 + mm) * 16 + 4 * q;
#pragma unroll
        for (int i = 0; i < 4; ++i) {
          const int o = ob + i;
          if (o >= C1) sm.ep[px * 72 + (o - C1)] = (bf16)acc[nt][mm][i];
        }
      }
    }
    __syncthreads();
#pragma unroll
    for (int p = 0; p < 4; ++p) {
      int id = tid + p * 256;               // 1024 chunks = 128 px x 8
      int c8 = id & 7, px = id >> 3;
      bf16x8 v = *(const bf16x8*)&sm.ep[px * 72 + c8 * 8];
      const int r = px >> 6, wv2 = px & 63;
      *(bf16x8*)&padout[(((size_t)(b * 64 + h0 + r)) * 64 + wv2) * 64 + c8 * 8] = v;
    }
  }
}

extern "C" void kernel_launch(void* const* d_in, const int* in_sizes, int n_in,
                              void* d_out, int out_size, void* d_ws, size_t ws_size,
                              hipStream_t stream) {
  QArgs qa;
  const float* x = (const float*)d_in[0];
  for (int L = 0; L < 5; ++L) {
    qa.w[L]  = (const float*)d_in[1 + 5 * L];
    qa.g[L]  = (const float*)d_in[2 + 5 * L];
    qa.bb[L] = (const float*)d_in[3 + 5 * L];
    qa.m[L]  = (const float*)d_in[4 + 5 * L];
    qa.v[L]  = (const float*)d_in[5 + 5 * L];
  }
  // workspace carve (16B aligned), ~85 MB total; tT aliases xT (xT dead by stage 3)
  char* p = (char*)d_ws;
  bf16* wpk1 = (bf16*)p; p += (size_t)192 * 2304 * 2;
  bf16* wpk2 = (bf16*)p; p += (size_t)128 * 576 * 2;
  bf16* wpk3 = (bf16*)p; p += (size_t)64 * 576 * 2;
  float* a1 = (float*)p; p += 1024;
  float* b1 = (float*)p; p += 1024;
  float* a2 = (float*)p; p += 1024;
  float* b2 = (float*)p; p += 1024;
  float* a3 = (float*)p; p += 1024;
  float* b3 = (float*)p; p += 1024;
  bf16* xT   = (bf16*)p; p += (size_t)32 * 64 * 64 * 256 * 2;  // 67.1 MB
  bf16* stem = (bf16*)p; p += (size_t)32 * 64 * 64 * 64 * 2;   // 16.8 MB
  bf16* tbuf = xT;                                             // alias: xT dead after stage 1
  qa.wpk[0] = wpk1; qa.wpk[1] = wpk2; qa.wpk[2] = wpk3;
  qa.alpha[0] = a1; qa.alpha[1] = a2; qa.alpha[2] = a3;
  qa.beta[0]  = b1; qa.beta[1]  = b2; qa.beta[2]  = b3;

  quant_kernel<<<384, 256, 0, stream>>>(qa);
  transpose_k<<<32 * 64 * 4, 256, 0, stream>>>(x, xT);

  // stage 1: xT -> c3 (fp32 ch 0..127) + stem (bf16 c-minor)
  conv_k<256, 12, 3, 128, true ><<<1024, 256, 0, stream>>>(xT,   wpk1, a1, b1, (float*)d_out, 0,   stem);
  // stage 2: stem -> c5 (fp32 ch 128..191) + t (bf16 c-minor, aliases xT)
  conv_k< 64,  8, 2,  64, true ><<<1024, 256, 0, stream>>>(stem, wpk2, a2, b2, (float*)d_out, 128, tbuf);
  // stage 3: t -> c7 (fp32 ch 192..255)
  conv_k< 64,  4, 1,  64, false><<<1024, 256, 0, stream>>>(tbuf, wpk3, a3, b3, (float*)d_out, 192, nullptr);
}

// Round 3
// 542.448 us; speedup vs baseline: 1.3381x; 1.0902x over previous
//
#include <hip/hip_runtime.h>
#include <stdint.h>

#define EPSF 1e-5f

typedef __bf16 bf16;
typedef __attribute__((ext_vector_type(8))) __bf16 bf16x8;
typedef __attribute__((ext_vector_type(4))) float f32x4;

// ---------------- quantization + BN-fold + MFMA-fragment prepack -----------------
// k-order: k = (kh*3+kw)*CIN + c (c-minor). A-frag prepack: wpk[ks][mt][lane][j],
// lane = kq*16 + (o&15), j = k&7.  (layout verified rounds 1-2)
// Median via exact 8-bit radix select on |w| bit patterns (monotone for floats>=0).
struct QArgs {
  const float* w[5];
  const float* g[5];
  const float* bb[5];
  const float* m[5];
  const float* v[5];
  bf16* wpk[3];
  float* alpha[3];
  float* beta[3];
};

__global__ __launch_bounds__(256)
void quant_kernel(QArgs qa) {
  __shared__ unsigned hist[256];
  __shared__ unsigned sbin, srank;
  const int tid = threadIdx.x;
  const int blk = blockIdx.x;
  int layer, o;
  if (blk < 128)      { layer = 0; o = blk; }
  else if (blk < 192) { layer = 1; o = blk - 128; }
  else if (blk < 256) { layer = 2; o = blk - 192; }
  else if (blk < 320) { layer = 3; o = blk - 256; }
  else                { layer = 4; o = blk - 320; }
  const int I_[5]     = {256, 256, 64, 64, 64};
  const int gemm_[5]  = {0, 0, 1, 1, 2};
  const int obase_[5] = {0, 128, 0, 64, 0};
  const int gNMT[3]   = {12, 8, 4};
  const int I = I_[layer];
  const int n = I * 9;                       // 2304 or 576
  const float* w = qa.w[layer] + (size_t)o * n;

  unsigned key[9]; int cnt = 0;
  for (int i = tid; i < n; i += 256) key[cnt++] = __float_as_uint(fabsf(w[i]));

  float mid[2];
  for (int sel = 0; sel < 2; ++sel) {
    unsigned rank = (unsigned)(n / 2 - 1 + sel);
    unsigned pfx = 0;
    for (int pass = 0; pass < 4; ++pass) {
      const int shift = 24 - 8 * pass;
      const unsigned himask = (pass == 0) ? 0u : (0xFFFFFFFFu << (shift + 8));
      hist[tid] = 0;
      __syncthreads();
      for (int j = 0; j < cnt; ++j)
        if ((key[j] & himask) == pfx) atomicAdd(&hist[(key[j] >> shift) & 255], 1u);
      __syncthreads();
      if (tid == 0) {
        unsigned cum = 0;
        for (int bb2 = 0; bb2 < 256; ++bb2) {
          unsigned h = hist[bb2];
          if (cum + h > rank) { sbin = (unsigned)bb2; srank = rank - cum; break; }
          cum += h;
        }
      }
      __syncthreads();
      pfx |= sbin << shift;
      rank = srank;
    }
    mid[sel] = __uint_as_float(pfx);
  }
  const float s = fmaxf(0.5f * (mid[0] + mid[1]), EPSF);

  const int g  = gemm_[layer];
  const int ob = obase_[layer];
  const int NMT = gNMT[g];
  if (tid == 0) {
    float inv = qa.g[layer][o] / sqrtf(qa.v[layer][o] + EPSF);
    qa.alpha[g][ob + o] = s * inv;
    qa.beta[g][ob + o]  = qa.bb[layer][o] - qa.m[layer][o] * inv;
  }
  const int og  = ob + o;
  const int mt  = og >> 4;
  const int l16 = og & 15;
  bf16* wp = qa.wpk[g];
  for (int i = tid; i < n; i += 256) {
    float t = rintf(w[i] / s);
    t = fmaxf(-1.f, fminf(1.f, t));
    int c = i / 9, pos = i % 9;
    int k = pos * I + c;
    int ks = k >> 5, kq = (k >> 3) & 3, jj = k & 7;
    wp[((size_t)((ks * NMT + mt) * 64 + kq * 16 + l16)) * 8 + jj] = (bf16)t;
  }
}

// ---------------- NCHW fp32 -> c-minor bf16 transpose: xT[b][h][w][256] ----------
__global__ __launch_bounds__(256)
void transpose_k(const float* __restrict__ x, bf16* __restrict__ xT) {
  __shared__ float tile[64 * 66];
  const int tid = threadIdx.x;
  const int blk = blockIdx.x;
  const int cg = blk & 3;
  const int h  = (blk >> 2) & 63;
  const int b  = blk >> 8;
  const int w  = tid & 63;
  const int cb = tid >> 6;
#pragma unroll
  for (int p = 0; p < 16; ++p) {
    int c = cb * 16 + p;
    tile[w * 66 + c] = x[(((size_t)(b * 256 + cg * 64 + c)) * 64 + h) * 64 + w];
  }
  __syncthreads();
#pragma unroll
  for (int p = 0; p < 2; ++p) {
    int id = tid + p * 256;
    int c8 = id & 7, w2 = id >> 3;
    const float* src = &tile[w2 * 66 + c8 * 8];
    bf16x8 v;
#pragma unroll
    for (int j = 0; j < 8; ++j) v[j] = (bf16)src[j];
    *(bf16x8*)&xT[(((size_t)(b * 64 + h)) * 64 + w2) * 256 + cg * 64 + c8 * 8] = v;
  }
}

// ---------------- implicit-GEMM conv3x3 (pad=1) + fused BN + SiLU ----------------
// 512 thr = 8 waves. Block tile: 128 px (2 rows x 64 w) x NMT*16 ch.
// Wave = 1 row x 64 px (4 n-tiles) x MM m-tiles (rw = wave>>2, mgrp = wave&3).
// Double-buffered LDS B-staging, ONE barrier per 32-ch c-iter; global prefetch for
// iter i+1 issued before MFMA phase of i (in flight across the whole phase).
// A-fragments global->VGPR, software-pipelined one tap ahead.
template<int CIN, int NMT, int MM, int C1, bool HASPAD>
__global__ __launch_bounds__(512, 4)
void conv_k(const bf16* __restrict__ xin,   // [B][64][64][CIN] c-minor bf16
            const bf16* __restrict__ wpk,
            const float* __restrict__ alpha,
            const float* __restrict__ beta,
            float* __restrict__ out, int chan_off,
            bf16* __restrict__ padout) {    // [B][64][64][64] c-minor bf16
  constexpr int NC = CIN / 32;
  __shared__ union U {
    bf16 xs[2][4 * 66 * 40];   // 2 x 21.1 KB
    bf16 ep[128 * 72];         // 18.4 KB epilogue transpose buffer
  } sm;

  const int tid  = threadIdx.x;
  const int wave = tid >> 6;
  const int lane = tid & 63;
  const int q    = lane >> 4;
  const int t16  = lane & 15;
  const int rw   = wave >> 2;            // output row within block (0/1)
  const int mt0  = (wave & 3) * MM;
  const int b    = blockIdx.x >> 5;
  const int h0   = (blockIdx.x & 31) << 1;

  // staging geometry: 1056 b128 chunks = 4 rows x 66 cols x 4 ch-chunks
  size_t gbase[3];
  int    loff[3];
  bool   gval[3], lval[3];
#pragma unroll
  for (int p = 0; p < 3; ++p) {
    int id = tid + p * 512;
    lval[p] = (id < 1056);
    int c8 = id & 3, rj = id >> 2;
    int j = rj % 66, r = rj / 66;
    int hh = h0 + r - 1, ww = j - 1;
    gval[p] = lval[p] && ((unsigned)hh < 64u) && ((unsigned)ww < 64u);
    gbase[p] = (((size_t)(b * 64 + hh)) * 64 + ww) * CIN + c8 * 8;
    loff[p] = (r * 66 + j) * 40 + c8 * 8;
  }

  f32x4 acc[4][MM] = {};
  bf16x8 stg[3];

  // prologue: stage c-iter 0 into buffer 0
#pragma unroll
  for (int p = 0; p < 3; ++p) {
    bf16x8 v = {};
    if (gval[p]) v = *(const bf16x8*)&xin[gbase[p]];
    stg[p] = v;
  }
#pragma unroll
  for (int p = 0; p < 3; ++p)
    if (lval[p]) *(bf16x8*)&sm.xs[0][loff[p]] = stg[p];

  for (int ci = 0; ci < NC; ++ci) {
    const int cur = ci & 1;
    __syncthreads();                     // buf[cur] writes visible to all waves
    if (ci + 1 < NC) {                   // issue next iter's global loads now
      const int c0n = (ci + 1) * 32;
#pragma unroll
      for (int p = 0; p < 3; ++p) {
        bf16x8 v = {};
        if (gval[p]) v = *(const bf16x8*)&xin[gbase[p] + c0n];
        stg[p] = v;
      }
    }
    // MFMA phase over 9 taps, A prefetched one tap ahead
    bf16x8 aA[MM], aB[MM];
#pragma unroll
    for (int mm = 0; mm < MM; ++mm)
      aA[mm] = *(const bf16x8*)&wpk[((size_t)(ci * NMT + mt0 + mm) * 64 + lane) * 8];
#pragma unroll
    for (int pos = 0; pos < 9; ++pos) {
      bf16x8* ac = (pos & 1) ? aB : aA;
      bf16x8* an = (pos & 1) ? aA : aB;
      if (pos < 8) {
        const int ksn = (pos + 1) * NC + ci;
#pragma unroll
        for (int mm = 0; mm < MM; ++mm)
          an[mm] = *(const bf16x8*)&wpk[((size_t)(ksn * NMT + mt0 + mm) * 64 + lane) * 8];
      }
      const int kh = pos / 3, kw = pos % 3;
      const int row = rw + kh;
#pragma unroll
      for (int nt = 0; nt < 4; ++nt) {
        const int col = nt * 16 + t16 + kw;
        const bf16x8 bf = *(const bf16x8*)&sm.xs[cur][(row * 66 + col) * 40 + q * 8];
#pragma unroll
        for (int mm = 0; mm < MM; ++mm)
          acc[nt][mm] = __builtin_amdgcn_mfma_f32_16x16x32_bf16(ac[mm], bf, acc[nt][mm], 0, 0, 0);
      }
    }
    if (ci + 1 < NC) {                   // drain prefetch into the other buffer
#pragma unroll
      for (int p = 0; p < 3; ++p)
        if (lval[p]) *(bf16x8*)&sm.xs[1 - cur][loff[p]] = stg[p];
    }
  }

  // epilogue: BN + SiLU; fp32 NCHW stores for o < C1
  const int h = h0 + rw;
#pragma unroll
  for (int mm = 0; mm < MM; ++mm) {
    const int o0 = (mt0 + mm) * 16 + 4 * q;
    float av[4], bv[4];
#pragma unroll
    for (int i = 0; i < 4; ++i) { av[i] = alpha[o0 + i]; bv[i] = beta[o0 + i]; }
#pragma unroll
    for (int nt = 0; nt < 4; ++nt) {
      const int wv = nt * 16 + t16;
#pragma unroll
      for (int i = 0; i < 4; ++i) {
        float v = acc[nt][mm][i] * av[i] + bv[i];
        float sg = v / (1.f + __expf(-v));
        acc[nt][mm][i] = sg;
        if (o0 < C1)
          out[(((size_t)(b * 256 + chan_off + o0 + i)) * 64 + h) * 64 + wv] = sg;
      }
    }
  }
  if (HASPAD) {
    __syncthreads();                     // xs dead -> reuse as ep
#pragma unroll
    for (int mm = 0; mm < MM; ++mm) {
      const int o0 = (mt0 + mm) * 16 + 4 * q;
      if (o0 >= C1) {
#pragma unroll
        for (int nt = 0; nt < 4; ++nt) {
          const int px = rw * 64 + nt * 16 + t16;
          union { bf16 h4[4]; uint2 u; } pk;
#pragma unroll
          for (int i = 0; i < 4; ++i) pk.h4[i] = (bf16)acc[nt][mm][i];
          *(uint2*)&sm.ep[px * 72 + (o0 - C1)] = pk.u;
        }
      }
    }
    __syncthreads();
#pragma unroll
    for (int p = 0; p < 2; ++p) {
      int id = tid + p * 512;            // 1024 chunks = 128 px x 8
      int c8 = id & 7, px = id >> 3;
      bf16x8 v = *(const bf16x8*)&sm.ep[px * 72 + c8 * 8];
      const int r = px >> 6, wv2 = px & 63;
      *(bf16x8*)&padout[(((size_t)(b * 64 + h0 + r)) * 64 + wv2) * 64 + c8 * 8] = v;
    }
  }
}

extern "C" void kernel_launch(void* const* d_in, const int* in_sizes, int n_in,
                              void* d_out, int out_size, void* d_ws, size_t ws_size,
                              hipStream_t stream) {
  QArgs qa;
  const float* x = (const float*)d_in[0];
  for (int L = 0; L < 5; ++L) {
    qa.w[L]  = (const float*)d_in[1 + 5 * L];
    qa.g[L]  = (const float*)d_in[2 + 5 * L];
    qa.bb[L] = (const float*)d_in[3 + 5 * L];
    qa.m[L]  = (const float*)d_in[4 + 5 * L];
    qa.v[L]  = (const float*)d_in[5 + 5 * L];
  }
  char* p = (char*)d_ws;
  bf16* wpk1 = (bf16*)p; p += (size_t)192 * 2304 * 2;
  bf16* wpk2 = (bf16*)p; p += (size_t)128 * 576 * 2;
  bf16* wpk3 = (bf16*)p; p += (size_t)64 * 576 * 2;
  float* a1 = (float*)p; p += 1024;
  float* b1 = (float*)p; p += 1024;
  float* a2 = (float*)p; p += 1024;
  float* b2 = (float*)p; p += 1024;
  float* a3 = (float*)p; p += 1024;
  float* b3 = (float*)p; p += 1024;
  bf16* xT   = (bf16*)p; p += (size_t)32 * 64 * 64 * 256 * 2;  // 67.1 MB
  bf16* stem = (bf16*)p; p += (size_t)32 * 64 * 64 * 64 * 2;   // 16.8 MB
  bf16* tbuf = xT;                                             // alias: xT dead after stage 1
  qa.wpk[0] = wpk1; qa.wpk[1] = wpk2; qa.wpk[2] = wpk3;
  qa.alpha[0] = a1; qa.alpha[1] = a2; qa.alpha[2] = a3;
  qa.beta[0]  = b1; qa.beta[1]  = b2; qa.beta[2]  = b3;

  quant_kernel<<<384, 256, 0, stream>>>(qa);
  transpose_k<<<32 * 64 * 4, 256, 0, stream>>>(x, xT);

  conv_k<256, 12, 3, 128, true ><<<1024, 512, 0, stream>>>(xT,   wpk1, a1, b1, (float*)d_out, 0,   stem);
  conv_k< 64,  8, 2,  64, true ><<<1024, 512, 0, stream>>>(stem, wpk2, a2, b2, (float*)d_out, 128, tbuf);
  conv_k< 64,  4, 1,  64, false><<<1024, 512, 0, stream>>>(tbuf, wpk3, a3, b3, (float*)d_out, 192, nullptr);
}